// Round 14
// baseline (179.399 us; speedup 1.0000x reference)
//
#include <hip/hip_runtime.h>
#include <hip/hip_bf16.h>
#include <math.h>

#define EN 8192
#define EL 8192
#define D  256
#define NG 64
#define INF_BITS 0x7f800000u

typedef __attribute__((ext_vector_type(8))) short  bf16x8;
typedef __attribute__((ext_vector_type(4))) float  f32x4;

__device__ __forceinline__ unsigned short f2bf(float f) {
    unsigned u = __float_as_uint(f);
    unsigned r = (u + 0x7fffu + ((u >> 16) & 1u)) >> 16;   // RNE
    return (unsigned short)r;
}

// min-butterfly over each 16-lane row, fused v_min_f32+DPP (1 instr/step,
// VALU pipe, zero LDS traffic). Verified R9 (mov_dpp form) / R12 (fused).
__device__ __forceinline__ float dpp_min16(float m) {
    float t;
    asm("v_min_f32 %0, %1, %2 quad_perm:[1,0,3,2] row_mask:0xf bank_mask:0xf"
        : "=v"(t) : "v"(m), "v"(m));
    asm("v_min_f32 %0, %1, %2 quad_perm:[2,3,0,1] row_mask:0xf bank_mask:0xf"
        : "=v"(m) : "v"(t), "v"(t));
    asm("v_min_f32 %0, %1, %2 row_ror:4 row_mask:0xf bank_mask:0xf"
        : "=v"(t) : "v"(m), "v"(m));
    asm("v_min_f32 %0, %1, %2 row_ror:8 row_mask:0xf bank_mask:0xf"
        : "=v"(m) : "v"(t), "v"(t));
    return m;
}

// lane-wise xor16 / xor32 min via gfx950 permlane swaps (VALU pipe; replaces
// ds_bpermute-backed __shfl_xor). With a=b=m, v_permlane16_swap_b32 leaves
// a = {r0,r0,r2,r2}, b = {r1,r1,r3,r3} (16-lane rows) -> fminf(a,b) is the
// lane-wise min over {l, l^16}. Analogous for the 32-lane swap -> {l, l^32}.
__device__ __forceinline__ float pl16_min(float m) {
    float a = m, b = m;
    asm volatile("v_permlane16_swap_b32 %0, %1" : "+v"(a), "+v"(b));
    return fminf(a, b);
}
__device__ __forceinline__ float pl32_min(float m) {
    float a = m, b = m;
    asm volatile("v_permlane32_swap_b32 %0, %1" : "+v"(a), "+v"(b));
    return fminf(a, b);
}
// 3-input min (T17): single VOP3 instruction.
__device__ __forceinline__ float fmin3(float a, float b, float c) {
    float d;
    asm("v_min3_f32 %0, %1, %2, %3" : "=v"(d) : "v"(a), "v"(b), "v"(c));
    return d;
}

// ---------------- kernel 1: fused init + edge features ----------------
// blocks [0,1024): fill bufN/bufL (contiguous 4 MB) with +inf via uint4
// blocks [1024,3072): edge features for node set
// blocks [3072,5120): edge features for label set
__global__ void prep(const float* __restrict__ h,
                     const int* __restrict__ node_edge,
                     const int* __restrict__ label_edge,
                     unsigned short* __restrict__ efn, float* __restrict__ normN,
                     unsigned short* __restrict__ efl, float* __restrict__ normL,
                     unsigned* __restrict__ inf_buf)
{
    int b = blockIdx.x;
    if (b < 1024) {
        uint4 v = make_uint4(INF_BITS, INF_BITS, INF_BITS, INF_BITS);
        ((uint4*)inf_buf)[b * 256 + threadIdx.x] = v;
        return;
    }
    b -= 1024;
    const int* edges; unsigned short* ef; float* norm;
    if (b < 2048) { edges = node_edge;  ef = efn; norm = normN; }
    else          { b -= 2048; edges = label_edge; ef = efl; norm = normL; }

    int wave = threadIdx.x >> 6;
    int lane = threadIdx.x & 63;
    int e = b * 4 + wave;
    int a  = edges[e];
    int bb = edges[EN + e];          // En == El == 8192
    float4 va = ((const float4*)(h + (size_t)a  * D))[lane];
    float4 vb = ((const float4*)(h + (size_t)bb * D))[lane];
    float4 f;
    f.x = 0.5f * (va.x + vb.x);
    f.y = 0.5f * (va.y + vb.y);
    f.z = 0.5f * (va.z + vb.z);
    f.w = 0.5f * (va.w + vb.w);
    float sq = f.x*f.x + f.y*f.y + f.z*f.z + f.w*f.w;
    ushort4 pk;
    pk.x = f2bf(f.x); pk.y = f2bf(f.y); pk.z = f2bf(f.z); pk.w = f2bf(f.w);
    ((ushort4*)(ef + (size_t)e * D))[lane] = pk;
    #pragma unroll
    for (int off = 1; off < 64; off <<= 1)
        sq += __shfl_xor(sq, off, 64);
    if (lane == 0) norm[e] = sq;
}

// ---------------- kernel 2: fused GEMM + sq-distance + segmented min ----------------
// R13 = R12 (80.3 us best: XCD swizzle + counted-vmcnt pipeline + fused-DPP
// row-min + setprio) + epilogue finished off the LDS pipe:
//   - col-min __shfl_xor(16/32) (ds_bpermute) -> permlane16/32_swap (VALU)
//   - 8- and 4-element min chains -> v_min3_f32 trees (7->4 ops, dep 28->12cy)
// Established rules: both MFMA operands MUST go through global_load_lds
// (R7/R11); 128x128 dbuf + 2 blocks/CU geometry (R3/R8 falsified others).
#define BARRIER()  asm volatile("s_barrier" ::: "memory")
#define VMCNT4()   asm volatile("s_waitcnt vmcnt(4)" ::: "memory")
#define VMCNT0()   asm volatile("s_waitcnt vmcnt(0)" ::: "memory")

__launch_bounds__(512, 4)
__global__ void dist_min(const unsigned short* __restrict__ A,   // ef_n [EN][D]
                         const unsigned short* __restrict__ B,   // ef_l [EL][D]
                         const float* __restrict__ normN,
                         const float* __restrict__ normL,
                         const int* __restrict__ node_batch,
                         const int* __restrict__ label_batch,
                         unsigned* __restrict__ bufN,  // [EN][NG] min sq-dist bits
                         unsigned* __restrict__ bufL)  // [NG][EL] min sq-dist bits
{
    __shared__ unsigned short As[2][128 * 64];
    __shared__ unsigned short Bs[2][128 * 64];

    const int tid  = threadIdx.x;
    const int lane = tid & 63;
    const int wave = tid >> 6;          // 0..7
    const int quad = lane >> 4;
    const int lc   = lane & 15;

    // XCD-region swizzle (grid is (64, 64) = 4096 blocks, x-fastest linear)
    // 8 regions of 32 row-tiles x 16 col-tiles -> bijective; 3 MB/XCD < L2
    const int lin    = blockIdx.y * 64 + blockIdx.x;   // 0..4095
    const int xcd    = lin & 7;
    const int within = lin >> 3;        // 0..511
    const int tx     = within & 15;     // col tile inside 32x16 region
    const int ty     = within >> 4;     // row tile inside region, 0..31
    const int m0 = ((xcd >> 2) * 32 + ty) * 128;
    const int n0 = ((xcd & 3) * 16 + tx) * 128;

    const int wr   = (wave >> 1) * 32;  // 4 row groups of 32
    const int wc   = (wave & 1) * 64;   // 2 col groups of 64

    f32x4 acc[2][4];
    #pragma unroll
    for (int i = 0; i < 2; ++i)
        #pragma unroll
        for (int j = 0; j < 4; ++j) {
            f32x4 z = {0.f, 0.f, 0.f, 0.f};
            acc[i][j] = z;
        }

    // stage tiles for K-step kt into LDS buffer `buf`; phys chunk (row, cc)
    // holds global chunk (row, cc^(row&7)); 4 glds per thread per call
    auto stage = [&](int buf, int kt) {
        #pragma unroll
        for (int t = 0; t < 2; ++t) {
            int c = t * 512 + tid;              // chunk id, linear in tid
            int row = c >> 3, cc = c & 7;
            int scc = cc ^ (row & 7);
            const unsigned short* gp = A + (size_t)(m0 + row) * D + kt * 64 + scc * 8;
            __builtin_amdgcn_global_load_lds(
                (const __attribute__((address_space(1))) void*)gp,
                (__attribute__((address_space(3))) void*)(As[buf] + c * 8), 16, 0, 0);
        }
        #pragma unroll
        for (int t = 0; t < 2; ++t) {
            int c = t * 512 + tid;
            int row = c >> 3, cc = c & 7;
            int scc = cc ^ (row & 7);
            const unsigned short* gp = B + (size_t)(n0 + row) * D + kt * 64 + scc * 8;
            __builtin_amdgcn_global_load_lds(
                (const __attribute__((address_space(1))) void*)gp,
                (__attribute__((address_space(3))) void*)(Bs[buf] + c * 8), 16, 0, 0);
        }
    };

    // one K=64 tile of MFMAs from buffer pair (Asb, Bsb)
    auto compute = [&](const unsigned short* Asb, const unsigned short* Bsb) {
        #pragma unroll
        for (int kk = 0; kk < 2; ++kk) {        // two k=32 steps
            bf16x8 af[2], bfv[4];
            #pragma unroll
            for (int mi = 0; mi < 2; ++mi)
                af[mi] = *(const bf16x8*)(Asb + (wr + mi*16 + lc) * 64
                                             + ((kk*4 + quad) ^ (lc & 7)) * 8);
            #pragma unroll
            for (int ni = 0; ni < 4; ++ni)
                bfv[ni] = *(const bf16x8*)(Bsb + (wc + ni*16 + lc) * 64
                                              + ((kk*4 + quad) ^ (lc & 7)) * 8);
            __builtin_amdgcn_s_setprio(1);
            #pragma unroll
            for (int mi = 0; mi < 2; ++mi)
                #pragma unroll
                for (int ni = 0; ni < 4; ++ni)
                    acc[mi][ni] = __builtin_amdgcn_mfma_f32_16x16x32_bf16(
                        af[mi], bfv[ni], acc[mi][ni], 0, 0, 0);
            __builtin_amdgcn_s_setprio(0);
        }
    };

    // ---- pipelined K-loop, K = 256 = 4 tiles of 64 ----
    stage(0, 0);
    stage(1, 1);
    VMCNT4();                     // tile 0's 4 glds landed (tile 1 in flight)
    BARRIER();

    compute(As[0], Bs[0]);        // kt = 0
    BARRIER();                    // all waves done reading buf 0
    stage(0, 2);
    VMCNT4();                     // tile 1 landed (tile 2 in flight)
    BARRIER();

    compute(As[1], Bs[1]);        // kt = 1
    BARRIER();                    // all waves done reading buf 1
    stage(1, 3);
    VMCNT4();                     // tile 2 landed (tile 3 in flight)
    BARRIER();

    compute(As[0], Bs[0]);        // kt = 2
    VMCNT0();                     // tile 3 landed
    BARRIER();

    compute(As[1], Bs[1]);        // kt = 3

    // ---- epilogue ----
    float nb[4]; int gl[4];
    #pragma unroll
    for (int ni = 0; ni < 4; ++ni) {
        int col = n0 + wc + ni*16 + lc;
        nb[ni] = normL[col];
        gl[ni] = label_batch[col];
    }
    float na[8]; int gr[8];
    #pragma unroll
    for (int mi = 0; mi < 2; ++mi)
        #pragma unroll
        for (int r = 0; r < 4; ++r) {
            int row = m0 + wr + mi*16 + quad*4 + r;
            na[mi*4 + r] = normN[row];
            gr[mi*4 + r] = node_batch[row];
        }

    // dot -> clamped squared distance (in place); sqrt deferred to finalize
    #pragma unroll
    for (int mi = 0; mi < 2; ++mi)
        #pragma unroll
        for (int ni = 0; ni < 4; ++ni)
            #pragma unroll
            for (int r = 0; r < 4; ++r)
                acc[mi][ni][r] = fmaxf(
                    fmaf(-2.0f, acc[mi][ni][r], na[mi*4 + r] + nb[ni]), 0.0f);

    const float FINF = __uint_as_float(INF_BITS);

    // ---- per-row min over columns, grouped by label graph ----
    // wave col window = [n0+wc, n0+wc+63] (sorted by label_batch)
    int glo = label_batch[n0 + wc], ghi = label_batch[n0 + wc + 63];
    if (glo == ghi) {
        // fast path: single label graph -> unsegmented min over 64 cols
        float rm[8];
        #pragma unroll
        for (int mi = 0; mi < 2; ++mi)
            #pragma unroll
            for (int r = 0; r < 4; ++r) {
                float m = fminf(fmin3(acc[mi][0][r], acc[mi][1][r], acc[mi][2][r]),
                                acc[mi][3][r]);
                rm[mi*4 + r] = dpp_min16(m);
            }
        if (lc == 0) {
            #pragma unroll
            for (int mi = 0; mi < 2; ++mi)
                #pragma unroll
                for (int r = 0; r < 4; ++r) {
                    int row = m0 + wr + mi*16 + quad*4 + r;
                    atomicMin(&bufN[row * NG + glo], __float_as_uint(rm[mi*4 + r]));
                }
        }
    } else {
        for (int g = glo; g <= ghi; ++g) {
            bool s0 = (gl[0] == g), s1 = (gl[1] == g), s2 = (gl[2] == g), s3 = (gl[3] == g);
            float rm[8];
            #pragma unroll
            for (int mi = 0; mi < 2; ++mi)
                #pragma unroll
                for (int r = 0; r < 4; ++r) {
                    float v0 = s0 ? acc[mi][0][r] : FINF;
                    float v1 = s1 ? acc[mi][1][r] : FINF;
                    float v2 = s2 ? acc[mi][2][r] : FINF;
                    float v3 = s3 ? acc[mi][3][r] : FINF;
                    rm[mi*4 + r] = dpp_min16(fminf(fmin3(v0, v1, v2), v3));
                }
            if (lc == 0) {
                #pragma unroll
                for (int mi = 0; mi < 2; ++mi)
                    #pragma unroll
                    for (int r = 0; r < 4; ++r) {
                        int row = m0 + wr + mi*16 + quad*4 + r;
                        atomicMin(&bufN[row * NG + g], __float_as_uint(rm[mi*4 + r]));
                    }
            }
        }
    }

    // ---- per-col min over rows, grouped by node graph ----
    // wave row window = [m0+wr, m0+wr+31] (sorted by node_batch)
    int rlo = node_batch[m0 + wr], rhi = node_batch[m0 + wr + 31];
    if (rlo == rhi) {
        // fast path: single node graph -> unsegmented min over 32 rows
        float cm[4];
        #pragma unroll
        for (int ni = 0; ni < 4; ++ni) {
            float m = fminf(fmin3(fmin3(acc[0][ni][0], acc[0][ni][1], acc[0][ni][2]),
                                  fmin3(acc[0][ni][3], acc[1][ni][0], acc[1][ni][1]),
                                  acc[1][ni][2]),
                            acc[1][ni][3]);
            m = pl16_min(m);
            m = pl32_min(m);
            cm[ni] = m;
        }
        if (quad == 0) {
            #pragma unroll
            for (int ni = 0; ni < 4; ++ni) {
                int col = n0 + wc + ni*16 + lc;
                atomicMin(&bufL[rlo * EL + col], __float_as_uint(cm[ni]));
            }
        }
    } else {
        for (int g = rlo; g <= rhi; ++g) {
            float cm[4];
            #pragma unroll
            for (int ni = 0; ni < 4; ++ni) {
                float s[8];
                #pragma unroll
                for (int mi = 0; mi < 2; ++mi)
                    #pragma unroll
                    for (int r = 0; r < 4; ++r)
                        s[mi*4 + r] = (gr[mi*4 + r] == g) ? acc[mi][ni][r] : FINF;
                float m = fminf(fmin3(fmin3(s[0], s[1], s[2]),
                                      fmin3(s[3], s[4], s[5]), s[6]),
                                s[7]);
                m = pl16_min(m);
                m = pl32_min(m);
                cm[ni] = m;
            }
            if (quad == 0) {
                #pragma unroll
                for (int ni = 0; ni < 4; ++ni) {
                    int col = n0 + wc + ni*16 + lc;
                    atomicMin(&bufL[g * EL + col], __float_as_uint(cm[ni]));
                }
            }
        }
    }
}

// ---------------- kernel 3: segment means + combine ----------------
__device__ __forceinline__ int lbound(const int* __restrict__ a, int n, int v) {
    int lo = 0, hi = n;
    while (lo < hi) { int mid = (lo + hi) >> 1; if (a[mid] < v) lo = mid + 1; else hi = mid; }
    return lo;
}

// one block per node-graph gn; MUST be launched with 1024 threads
__global__ void finalize(const unsigned* __restrict__ bufN,
                         const unsigned* __restrict__ bufL,
                         const int* __restrict__ node_batch,
                         const int* __restrict__ label_batch,
                         float* __restrict__ out)
{
    __shared__ float sN[NG];   // sum over rows of -dist, per label graph
    __shared__ float sL[NG];   // sum over cols of -dist, per label graph
    int gn  = blockIdx.x;
    int tid = threadIdx.x;
    if (tid < NG) { sN[tid] = 0.0f; sL[tid] = 0.0f; }
    __syncthreads();

    int ns = lbound(node_batch, EN, gn);
    int ne = lbound(node_batch, EN, gn + 1);

    // part 1: bufN slice [ns:ne) x NG -> per-label sums (coalesced across t)
    {
        int t = tid & 63, strip = tid >> 6;          // 16 row strips
        float acc = 0.0f;
        for (int i = ns + strip; i < ne; i += 16) {
            unsigned b = bufN[i * NG + t];
            if (b != INF_BITS) acc -= sqrtf(__uint_as_float(b));
        }
        atomicAdd(&sN[t], acc);
    }

    // part 2: bufL row gn (8192 cols, coalesced), scatter by label graph
    for (int j = tid; j < EL; j += 1024) {
        unsigned b = bufL[gn * EL + j];
        if (b != INF_BITS) {
            int g = label_batch[j];
            atomicAdd(&sL[g], -sqrtf(__uint_as_float(b)));
        }
    }
    __syncthreads();

    if (tid < NG) {
        int t = tid;
        int cn = ne - ns;
        int ls = lbound(label_batch, EL, t);
        int le = lbound(label_batch, EL, t + 1);
        int cl = le - ls;
        float out_n = sN[t] / (float)(cn > 0 ? cn : 1);
        float out_l = sL[t] / (float)(cl > 0 ? cl : 1);
        out[gn * NG + t] = 0.5f * (out_n + out_l);
    }
}

extern "C" void kernel_launch(void* const* d_in, const int* in_sizes, int n_in,
                              void* d_out, int out_size, void* d_ws, size_t ws_size,
                              hipStream_t stream)
{
    const float* h          = (const float*)d_in[0];
    const int* node_edge    = (const int*)d_in[1];
    const int* node_batch   = (const int*)d_in[2];
    const int* label_edge   = (const int*)d_in[3];
    const int* label_batch  = (const int*)d_in[4];
    float* out = (float*)d_out;

    char* ws = (char*)d_ws;
    unsigned short* efn = (unsigned short*)ws; ws += (size_t)EN * D * 2;
    unsigned short* efl = (unsigned short*)ws; ws += (size_t)EL * D * 2;
    float* normN = (float*)ws;                 ws += (size_t)EN * 4;
    float* normL = (float*)ws;                 ws += (size_t)EL * 4;
    unsigned* bufN = (unsigned*)ws;            ws += (size_t)EN * NG * 4;
    unsigned* bufL = (unsigned*)ws;            ws += (size_t)NG * EL * 4;

    // bufN,bufL contiguous: 1024 init blocks + 2048 + 2048 edge blocks
    prep<<<5120, 256, 0, stream>>>(h, node_edge, label_edge,
                                   efn, normN, efl, normL, bufN);
    dist_min<<<dim3(EL / 128, EN / 128), 512, 0, stream>>>(
        efn, efl, normN, normL, node_batch, label_batch, bufN, bufL);
    finalize<<<NG, 1024, 0, stream>>>(bufN, bufL, node_batch, label_batch, out);
}

// Round 15
// 178.223 us; speedup vs baseline: 1.0066x; 1.0066x over previous
//
#include <hip/hip_runtime.h>
#include <hip/hip_bf16.h>
#include <math.h>

#define EN 8192
#define EL 8192
#define D  256
#define NG 64
#define INF_BITS 0x7f800000u

typedef __attribute__((ext_vector_type(8))) short  bf16x8;
typedef __attribute__((ext_vector_type(4))) float  f32x4;

__device__ __forceinline__ unsigned short f2bf(float f) {
    unsigned u = __float_as_uint(f);
    unsigned r = (u + 0x7fffu + ((u >> 16) & 1u)) >> 16;   // RNE
    return (unsigned short)r;
}

// min-butterfly over each 16-lane row, fused v_min_f32+DPP (1 instr/step,
// VALU pipe, zero LDS traffic). Verified R9 (mov_dpp form) / R12 (fused).
__device__ __forceinline__ float dpp_min16(float m) {
    float t;
    asm("v_min_f32 %0, %1, %2 quad_perm:[1,0,3,2] row_mask:0xf bank_mask:0xf"
        : "=v"(t) : "v"(m), "v"(m));
    asm("v_min_f32 %0, %1, %2 quad_perm:[2,3,0,1] row_mask:0xf bank_mask:0xf"
        : "=v"(m) : "v"(t), "v"(t));
    asm("v_min_f32 %0, %1, %2 row_ror:4 row_mask:0xf bank_mask:0xf"
        : "=v"(t) : "v"(m), "v"(m));
    asm("v_min_f32 %0, %1, %2 row_ror:8 row_mask:0xf bank_mask:0xf"
        : "=v"(m) : "v"(t), "v"(t));
    return m;
}

// lane-wise xor16 / xor32 min via gfx950 permlane swaps (VALU pipe; replaces
// ds_bpermute-backed __shfl_xor). Verified R13 (refcheck passed).
__device__ __forceinline__ float pl16_min(float m) {
    float a = m, b = m;
    asm volatile("v_permlane16_swap_b32 %0, %1" : "+v"(a), "+v"(b));
    return fminf(a, b);
}
__device__ __forceinline__ float pl32_min(float m) {
    float a = m, b = m;
    asm volatile("v_permlane32_swap_b32 %0, %1" : "+v"(a), "+v"(b));
    return fminf(a, b);
}
// 3-input min (T17): single VOP3 instruction.
__device__ __forceinline__ float fmin3(float a, float b, float c) {
    float d;
    asm("v_min3_f32 %0, %1, %2, %3" : "=v"(d) : "v"(a), "v"(b), "v"(c));
    return d;
}

// ---------------- kernel 1: fused init + edge features ----------------
// blocks [0,1024): fill bufN/bufL (contiguous 4 MB) with +inf via uint4
// blocks [1024,3072): edge features for node set
// blocks [3072,5120): edge features for label set
__global__ void prep(const float* __restrict__ h,
                     const int* __restrict__ node_edge,
                     const int* __restrict__ label_edge,
                     unsigned short* __restrict__ efn, float* __restrict__ normN,
                     unsigned short* __restrict__ efl, float* __restrict__ normL,
                     unsigned* __restrict__ inf_buf)
{
    int b = blockIdx.x;
    if (b < 1024) {
        uint4 v = make_uint4(INF_BITS, INF_BITS, INF_BITS, INF_BITS);
        ((uint4*)inf_buf)[b * 256 + threadIdx.x] = v;
        return;
    }
    b -= 1024;
    const int* edges; unsigned short* ef; float* norm;
    if (b < 2048) { edges = node_edge;  ef = efn; norm = normN; }
    else          { b -= 2048; edges = label_edge; ef = efl; norm = normL; }

    int wave = threadIdx.x >> 6;
    int lane = threadIdx.x & 63;
    int e = b * 4 + wave;
    int a  = edges[e];
    int bb = edges[EN + e];          // En == El == 8192
    float4 va = ((const float4*)(h + (size_t)a  * D))[lane];
    float4 vb = ((const float4*)(h + (size_t)bb * D))[lane];
    float4 f;
    f.x = 0.5f * (va.x + vb.x);
    f.y = 0.5f * (va.y + vb.y);
    f.z = 0.5f * (va.z + vb.z);
    f.w = 0.5f * (va.w + vb.w);
    float sq = f.x*f.x + f.y*f.y + f.z*f.z + f.w*f.w;
    ushort4 pk;
    pk.x = f2bf(f.x); pk.y = f2bf(f.y); pk.z = f2bf(f.z); pk.w = f2bf(f.w);
    ((ushort4*)(ef + (size_t)e * D))[lane] = pk;
    #pragma unroll
    for (int off = 1; off < 64; off <<= 1)
        sq += __shfl_xor(sq, off, 64);
    if (lane == 0) norm[e] = sq;
}

// ---------------- kernel 2: fused GEMM + sq-distance + segmented min ----------------
// R14 = R13 (80.3-80.7 us plateau: XCD swizzle + counted-vmcnt pipeline +
// fused-DPP/permlane/min3 epilogue + setprio) + T14 issue-early on the
// epilogue's block-constant loads. Mechanism: BARRIER()/VMCNT() carry
// "memory" clobbers, so the compiler CANNOT hoist the norm/batch loads
// above the K-loop -- they issued after the last MFMA and serialized
// ~200-600 cyc of L2 latency into the epilogue's dependent chains.
// Hoisting them before the prologue stage puts them in flight for the
// whole K-loop (values register-resident at epilogue entry; clobbers
// equally prevent sinking). Cost ~28 VGPR (52 -> ~80, under the 128 cap).
// Established rules: both MFMA operands via global_load_lds (R7/R11);
// 128x128 dbuf + 2 blocks/CU (R3/R8); BK=64 stride-128B zero-conflict (R2).
#define BARRIER()  asm volatile("s_barrier" ::: "memory")
#define VMCNT4()   asm volatile("s_waitcnt vmcnt(4)" ::: "memory")
#define VMCNT0()   asm volatile("s_waitcnt vmcnt(0)" ::: "memory")

__launch_bounds__(512, 4)
__global__ void dist_min(const unsigned short* __restrict__ A,   // ef_n [EN][D]
                         const unsigned short* __restrict__ B,   // ef_l [EL][D]
                         const float* __restrict__ normN,
                         const float* __restrict__ normL,
                         const int* __restrict__ node_batch,
                         const int* __restrict__ label_batch,
                         unsigned* __restrict__ bufN,  // [EN][NG] min sq-dist bits
                         unsigned* __restrict__ bufL)  // [NG][EL] min sq-dist bits
{
    __shared__ unsigned short As[2][128 * 64];
    __shared__ unsigned short Bs[2][128 * 64];

    const int tid  = threadIdx.x;
    const int lane = tid & 63;
    const int wave = tid >> 6;          // 0..7
    const int quad = lane >> 4;
    const int lc   = lane & 15;

    // XCD-region swizzle (grid is (64, 64) = 4096 blocks, x-fastest linear)
    // 8 regions of 32 row-tiles x 16 col-tiles -> bijective; 3 MB/XCD < L2
    const int lin    = blockIdx.y * 64 + blockIdx.x;   // 0..4095
    const int xcd    = lin & 7;
    const int within = lin >> 3;        // 0..511
    const int tx     = within & 15;     // col tile inside 32x16 region
    const int ty     = within >> 4;     // row tile inside region, 0..31
    const int m0 = ((xcd >> 2) * 32 + ty) * 128;
    const int n0 = ((xcd & 3) * 16 + tx) * 128;

    const int wr   = (wave >> 1) * 32;  // 4 row groups of 32
    const int wc   = (wave & 1) * 64;   // 2 col groups of 64

    // ---- T14: issue epilogue's block-constant loads BEFORE the K-loop ----
    // In flight during the whole pipeline; register-resident at epilogue.
    float nb[4]; int gl[4];
    #pragma unroll
    for (int ni = 0; ni < 4; ++ni) {
        int col = n0 + wc + ni*16 + lc;
        nb[ni] = normL[col];
        gl[ni] = label_batch[col];
    }
    float na[8]; int gr[8];
    #pragma unroll
    for (int mi = 0; mi < 2; ++mi)
        #pragma unroll
        for (int r = 0; r < 4; ++r) {
            int row = m0 + wr + mi*16 + quad*4 + r;
            na[mi*4 + r] = normN[row];
            gr[mi*4 + r] = node_batch[row];
        }
    const int glo = label_batch[n0 + wc], ghi = label_batch[n0 + wc + 63];
    const int rlo = node_batch[m0 + wr], rhi = node_batch[m0 + wr + 31];

    f32x4 acc[2][4];
    #pragma unroll
    for (int i = 0; i < 2; ++i)
        #pragma unroll
        for (int j = 0; j < 4; ++j) {
            f32x4 z = {0.f, 0.f, 0.f, 0.f};
            acc[i][j] = z;
        }

    // stage tiles for K-step kt into LDS buffer `buf`; phys chunk (row, cc)
    // holds global chunk (row, cc^(row&7)); 4 glds per thread per call
    auto stage = [&](int buf, int kt) {
        #pragma unroll
        for (int t = 0; t < 2; ++t) {
            int c = t * 512 + tid;              // chunk id, linear in tid
            int row = c >> 3, cc = c & 7;
            int scc = cc ^ (row & 7);
            const unsigned short* gp = A + (size_t)(m0 + row) * D + kt * 64 + scc * 8;
            __builtin_amdgcn_global_load_lds(
                (const __attribute__((address_space(1))) void*)gp,
                (__attribute__((address_space(3))) void*)(As[buf] + c * 8), 16, 0, 0);
        }
        #pragma unroll
        for (int t = 0; t < 2; ++t) {
            int c = t * 512 + tid;
            int row = c >> 3, cc = c & 7;
            int scc = cc ^ (row & 7);
            const unsigned short* gp = B + (size_t)(n0 + row) * D + kt * 64 + scc * 8;
            __builtin_amdgcn_global_load_lds(
                (const __attribute__((address_space(1))) void*)gp,
                (__attribute__((address_space(3))) void*)(Bs[buf] + c * 8), 16, 0, 0);
        }
    };

    // one K=64 tile of MFMAs from buffer pair (Asb, Bsb)
    auto compute = [&](const unsigned short* Asb, const unsigned short* Bsb) {
        #pragma unroll
        for (int kk = 0; kk < 2; ++kk) {        // two k=32 steps
            bf16x8 af[2], bfv[4];
            #pragma unroll
            for (int mi = 0; mi < 2; ++mi)
                af[mi] = *(const bf16x8*)(Asb + (wr + mi*16 + lc) * 64
                                             + ((kk*4 + quad) ^ (lc & 7)) * 8);
            #pragma unroll
            for (int ni = 0; ni < 4; ++ni)
                bfv[ni] = *(const bf16x8*)(Bsb + (wc + ni*16 + lc) * 64
                                              + ((kk*4 + quad) ^ (lc & 7)) * 8);
            __builtin_amdgcn_s_setprio(1);
            #pragma unroll
            for (int mi = 0; mi < 2; ++mi)
                #pragma unroll
                for (int ni = 0; ni < 4; ++ni)
                    acc[mi][ni] = __builtin_amdgcn_mfma_f32_16x16x32_bf16(
                        af[mi], bfv[ni], acc[mi][ni], 0, 0, 0);
            __builtin_amdgcn_s_setprio(0);
        }
    };

    // ---- pipelined K-loop, K = 256 = 4 tiles of 64 ----
    stage(0, 0);
    stage(1, 1);
    VMCNT4();                     // tile 0's 4 glds landed (tile 1 in flight)
    BARRIER();

    compute(As[0], Bs[0]);        // kt = 0
    BARRIER();                    // all waves done reading buf 0
    stage(0, 2);
    VMCNT4();                     // tile 1 landed (tile 2 in flight)
    BARRIER();

    compute(As[1], Bs[1]);        // kt = 1
    BARRIER();                    // all waves done reading buf 1
    stage(1, 3);
    VMCNT4();                     // tile 2 landed (tile 3 in flight)
    BARRIER();

    compute(As[0], Bs[0]);        // kt = 2
    VMCNT0();                     // tile 3 landed
    BARRIER();

    compute(As[1], Bs[1]);        // kt = 3

    // ---- epilogue (operand data already in registers) ----
    // dot -> clamped squared distance (in place); sqrt deferred to finalize
    #pragma unroll
    for (int mi = 0; mi < 2; ++mi)
        #pragma unroll
        for (int ni = 0; ni < 4; ++ni)
            #pragma unroll
            for (int r = 0; r < 4; ++r)
                acc[mi][ni][r] = fmaxf(
                    fmaf(-2.0f, acc[mi][ni][r], na[mi*4 + r] + nb[ni]), 0.0f);

    const float FINF = __uint_as_float(INF_BITS);

    // ---- per-row min over columns, grouped by label graph ----
    // wave col window = [n0+wc, n0+wc+63] (sorted by label_batch)
    if (glo == ghi) {
        // fast path: single label graph -> unsegmented min over 64 cols
        float rm[8];
        #pragma unroll
        for (int mi = 0; mi < 2; ++mi)
            #pragma unroll
            for (int r = 0; r < 4; ++r) {
                float m = fminf(fmin3(acc[mi][0][r], acc[mi][1][r], acc[mi][2][r]),
                                acc[mi][3][r]);
                rm[mi*4 + r] = dpp_min16(m);
            }
        if (lc == 0) {
            #pragma unroll
            for (int mi = 0; mi < 2; ++mi)
                #pragma unroll
                for (int r = 0; r < 4; ++r) {
                    int row = m0 + wr + mi*16 + quad*4 + r;
                    atomicMin(&bufN[row * NG + glo], __float_as_uint(rm[mi*4 + r]));
                }
        }
    } else {
        for (int g = glo; g <= ghi; ++g) {
            bool s0 = (gl[0] == g), s1 = (gl[1] == g), s2 = (gl[2] == g), s3 = (gl[3] == g);
            float rm[8];
            #pragma unroll
            for (int mi = 0; mi < 2; ++mi)
                #pragma unroll
                for (int r = 0; r < 4; ++r) {
                    float v0 = s0 ? acc[mi][0][r] : FINF;
                    float v1 = s1 ? acc[mi][1][r] : FINF;
                    float v2 = s2 ? acc[mi][2][r] : FINF;
                    float v3 = s3 ? acc[mi][3][r] : FINF;
                    rm[mi*4 + r] = dpp_min16(fminf(fmin3(v0, v1, v2), v3));
                }
            if (lc == 0) {
                #pragma unroll
                for (int mi = 0; mi < 2; ++mi)
                    #pragma unroll
                    for (int r = 0; r < 4; ++r) {
                        int row = m0 + wr + mi*16 + quad*4 + r;
                        atomicMin(&bufN[row * NG + g], __float_as_uint(rm[mi*4 + r]));
                    }
            }
        }
    }

    // ---- per-col min over rows, grouped by node graph ----
    // wave row window = [m0+wr, m0+wr+31] (sorted by node_batch)
    if (rlo == rhi) {
        // fast path: single node graph -> unsegmented min over 32 rows
        float cm[4];
        #pragma unroll
        for (int ni = 0; ni < 4; ++ni) {
            float m = fminf(fmin3(fmin3(acc[0][ni][0], acc[0][ni][1], acc[0][ni][2]),
                                  fmin3(acc[0][ni][3], acc[1][ni][0], acc[1][ni][1]),
                                  acc[1][ni][2]),
                            acc[1][ni][3]);
            m = pl16_min(m);
            m = pl32_min(m);
            cm[ni] = m;
        }
        if (quad == 0) {
            #pragma unroll
            for (int ni = 0; ni < 4; ++ni) {
                int col = n0 + wc + ni*16 + lc;
                atomicMin(&bufL[rlo * EL + col], __float_as_uint(cm[ni]));
            }
        }
    } else {
        for (int g = rlo; g <= rhi; ++g) {
            float cm[4];
            #pragma unroll
            for (int ni = 0; ni < 4; ++ni) {
                float s[8];
                #pragma unroll
                for (int mi = 0; mi < 2; ++mi)
                    #pragma unroll
                    for (int r = 0; r < 4; ++r)
                        s[mi*4 + r] = (gr[mi*4 + r] == g) ? acc[mi][ni][r] : FINF;
                float m = fminf(fmin3(fmin3(s[0], s[1], s[2]),
                                      fmin3(s[3], s[4], s[5]), s[6]),
                                s[7]);
                m = pl16_min(m);
                m = pl32_min(m);
                cm[ni] = m;
            }
            if (quad == 0) {
                #pragma unroll
                for (int ni = 0; ni < 4; ++ni) {
                    int col = n0 + wc + ni*16 + lc;
                    atomicMin(&bufL[g * EL + col], __float_as_uint(cm[ni]));
                }
            }
        }
    }
}

// ---------------- kernel 3: segment means + combine ----------------
__device__ __forceinline__ int lbound(const int* __restrict__ a, int n, int v) {
    int lo = 0, hi = n;
    while (lo < hi) { int mid = (lo + hi) >> 1; if (a[mid] < v) lo = mid + 1; else hi = mid; }
    return lo;
}

// one block per node-graph gn; MUST be launched with 1024 threads
__global__ void finalize(const unsigned* __restrict__ bufN,
                         const unsigned* __restrict__ bufL,
                         const int* __restrict__ node_batch,
                         const int* __restrict__ label_batch,
                         float* __restrict__ out)
{
    __shared__ float sN[NG];   // sum over rows of -dist, per label graph
    __shared__ float sL[NG];   // sum over cols of -dist, per label graph
    int gn  = blockIdx.x;
    int tid = threadIdx.x;
    if (tid < NG) { sN[tid] = 0.0f; sL[tid] = 0.0f; }
    __syncthreads();

    int ns = lbound(node_batch, EN, gn);
    int ne = lbound(node_batch, EN, gn + 1);

    // part 1: bufN slice [ns:ne) x NG -> per-label sums (coalesced across t)
    {
        int t = tid & 63, strip = tid >> 6;          // 16 row strips
        float acc = 0.0f;
        for (int i = ns + strip; i < ne; i += 16) {
            unsigned b = bufN[i * NG + t];
            if (b != INF_BITS) acc -= sqrtf(__uint_as_float(b));
        }
        atomicAdd(&sN[t], acc);
    }

    // part 2: bufL row gn (8192 cols, coalesced), scatter by label graph
    for (int j = tid; j < EL; j += 1024) {
        unsigned b = bufL[gn * EL + j];
        if (b != INF_BITS) {
            int g = label_batch[j];
            atomicAdd(&sL[g], -sqrtf(__uint_as_float(b)));
        }
    }
    __syncthreads();

    if (tid < NG) {
        int t = tid;
        int cn = ne - ns;
        int ls = lbound(label_batch, EL, t);
        int le = lbound(label_batch, EL, t + 1);
        int cl = le - ls;
        float out_n = sN[t] / (float)(cn > 0 ? cn : 1);
        float out_l = sL[t] / (float)(cl > 0 ? cl : 1);
        out[gn * NG + t] = 0.5f * (out_n + out_l);
    }
}

extern "C" void kernel_launch(void* const* d_in, const int* in_sizes, int n_in,
                              void* d_out, int out_size, void* d_ws, size_t ws_size,
                              hipStream_t stream)
{
    const float* h          = (const float*)d_in[0];
    const int* node_edge    = (const int*)d_in[1];
    const int* node_batch   = (const int*)d_in[2];
    const int* label_edge   = (const int*)d_in[3];
    const int* label_batch  = (const int*)d_in[4];
    float* out = (float*)d_out;

    char* ws = (char*)d_ws;
    unsigned short* efn = (unsigned short*)ws; ws += (size_t)EN * D * 2;
    unsigned short* efl = (unsigned short*)ws; ws += (size_t)EL * D * 2;
    float* normN = (float*)ws;                 ws += (size_t)EN * 4;
    float* normL = (float*)ws;                 ws += (size_t)EL * 4;
    unsigned* bufN = (unsigned*)ws;            ws += (size_t)EN * NG * 4;
    unsigned* bufL = (unsigned*)ws;            ws += (size_t)NG * EL * 4;

    // bufN,bufL contiguous: 1024 init blocks + 2048 + 2048 edge blocks
    prep<<<5120, 256, 0, stream>>>(h, node_edge, label_edge,
                                   efn, normN, efl, normL, bufN);
    dist_min<<<dim3(EL / 128, EN / 128), 512, 0, stream>>>(
        efn, efl, normN, normL, node_batch, label_batch, bufN, bufL);
    finalize<<<NG, 1024, 0, stream>>>(bufN, bufL, node_batch, label_batch, out);
}

// Round 16
// 178.075 us; speedup vs baseline: 1.0074x; 1.0008x over previous
//
#include <hip/hip_runtime.h>
#include <hip/hip_bf16.h>
#include <math.h>

#define EN 8192
#define EL 8192
#define D  256
#define NG 64
#define INF_BITS 0x7f800000u

typedef __attribute__((ext_vector_type(8))) short  bf16x8;
typedef __attribute__((ext_vector_type(4))) float  f32x4;

__device__ __forceinline__ unsigned short f2bf(float f) {
    unsigned u = __float_as_uint(f);
    unsigned r = (u + 0x7fffu + ((u >> 16) & 1u)) >> 16;   // RNE
    return (unsigned short)r;
}

// min-butterfly over each 16-lane row, fused v_min_f32+DPP (VALU pipe).
// Verified R9 (mov_dpp form) / R12 (fused) / R13/R14 (refcheck).
__device__ __forceinline__ float dpp_min16(float m) {
    float t;
    asm("v_min_f32 %0, %1, %2 quad_perm:[1,0,3,2] row_mask:0xf bank_mask:0xf"
        : "=v"(t) : "v"(m), "v"(m));
    asm("v_min_f32 %0, %1, %2 quad_perm:[2,3,0,1] row_mask:0xf bank_mask:0xf"
        : "=v"(m) : "v"(t), "v"(t));
    asm("v_min_f32 %0, %1, %2 row_ror:4 row_mask:0xf bank_mask:0xf"
        : "=v"(t) : "v"(m), "v"(m));
    asm("v_min_f32 %0, %1, %2 row_ror:8 row_mask:0xf bank_mask:0xf"
        : "=v"(m) : "v"(t), "v"(t));
    return m;
}

// lane-wise xor16 / xor32 min via gfx950 permlane swaps (VALU pipe).
__device__ __forceinline__ float pl16_min(float m) {
    float a = m, b = m;
    asm volatile("v_permlane16_swap_b32 %0, %1" : "+v"(a), "+v"(b));
    return fminf(a, b);
}
__device__ __forceinline__ float pl32_min(float m) {
    float a = m, b = m;
    asm volatile("v_permlane32_swap_b32 %0, %1" : "+v"(a), "+v"(b));
    return fminf(a, b);
}
// 3-input min (T17): single VOP3 instruction.
__device__ __forceinline__ float fmin3(float a, float b, float c) {
    float d;
    asm("v_min3_f32 %0, %1, %2, %3" : "=v"(d) : "v"(a), "v"(b), "v"(c));
    return d;
}

// ---------------- kernel 1: fused init + edge features ----------------
__global__ void prep(const float* __restrict__ h,
                     const int* __restrict__ node_edge,
                     const int* __restrict__ label_edge,
                     unsigned short* __restrict__ efn, float* __restrict__ normN,
                     unsigned short* __restrict__ efl, float* __restrict__ normL,
                     unsigned* __restrict__ inf_buf)
{
    int b = blockIdx.x;
    if (b < 1024) {
        uint4 v = make_uint4(INF_BITS, INF_BITS, INF_BITS, INF_BITS);
        ((uint4*)inf_buf)[b * 256 + threadIdx.x] = v;
        return;
    }
    b -= 1024;
    const int* edges; unsigned short* ef; float* norm;
    if (b < 2048) { edges = node_edge;  ef = efn; norm = normN; }
    else          { b -= 2048; edges = label_edge; ef = efl; norm = normL; }

    int wave = threadIdx.x >> 6;
    int lane = threadIdx.x & 63;
    int e = b * 4 + wave;
    int a  = edges[e];
    int bb = edges[EN + e];          // En == El == 8192
    float4 va = ((const float4*)(h + (size_t)a  * D))[lane];
    float4 vb = ((const float4*)(h + (size_t)bb * D))[lane];
    float4 f;
    f.x = 0.5f * (va.x + vb.x);
    f.y = 0.5f * (va.y + vb.y);
    f.z = 0.5f * (va.z + vb.z);
    f.w = 0.5f * (va.w + vb.w);
    float sq = f.x*f.x + f.y*f.y + f.z*f.z + f.w*f.w;
    ushort4 pk;
    pk.x = f2bf(f.x); pk.y = f2bf(f.y); pk.z = f2bf(f.z); pk.w = f2bf(f.w);
    ((ushort4*)(ef + (size_t)e * D))[lane] = pk;
    #pragma unroll
    for (int off = 1; off < 64; off <<= 1)
        sq += __shfl_xor(sq, off, 64);
    if (lane == 0) norm[e] = sq;
}

// ---------------- kernel 2: fused GEMM + sq-distance + segmented min ----------------
// R15 = R14 schedule with TWO column tiles per block (grid 4096 -> 2048),
// pipeline kept hot across the tile boundary:
//   - at the ct0->ct1 transition, ct1's k0/k1 are staged into the buffers
//     whose readers just finished (same barrier discipline as in-loop);
//   - ct0's epilogue runs between the wave's VMCNT4 and the barrier, so
//     its ~600 cyc of VALU+atomics overlap ct1-k1's flight instead of
//     serializing (halves pipeline fills, removes one drain per pair).
//   - ALL epilogue constants (both tiles) hoisted to kernel start so the
//     counted-vmcnt ledger sees only stage glds; post-epilogue waits are
//     conservative w.r.t. the atomics in vmcnt (safe, oldest-first).
// Mapping: 8 XCD regions x (32 row-tiles x 8 col-PAIRS); col tile =
// (xcd&3)*16 + txp*2 + ct covers 0..15 per region -> bijective over 64x64.
// Established rules: both MFMA operands via global_load_lds (R7/R11);
// 128x128 dbuf + 2 blocks/CU (R3/R8); BK=64 stride-128B zero-conflict (R2).
#define BARRIER()  asm volatile("s_barrier" ::: "memory")
#define VMCNT4()   asm volatile("s_waitcnt vmcnt(4)" ::: "memory")
#define VMCNT0()   asm volatile("s_waitcnt vmcnt(0)" ::: "memory")

__launch_bounds__(512, 4)
__global__ void dist_min(const unsigned short* __restrict__ A,   // ef_n [EN][D]
                         const unsigned short* __restrict__ B,   // ef_l [EL][D]
                         const float* __restrict__ normN,
                         const float* __restrict__ normL,
                         const int* __restrict__ node_batch,
                         const int* __restrict__ label_batch,
                         unsigned* __restrict__ bufN,  // [EN][NG] min sq-dist bits
                         unsigned* __restrict__ bufL)  // [NG][EL] min sq-dist bits
{
    __shared__ unsigned short As[2][128 * 64];
    __shared__ unsigned short Bs[2][128 * 64];

    const int tid  = threadIdx.x;
    const int lane = tid & 63;
    const int wave = tid >> 6;          // 0..7
    const int quad = lane >> 4;
    const int lc   = lane & 15;

    // XCD-region swizzle: grid (32, 64) = 2048 blocks, x-fastest linear.
    // 8 regions of 32 row-tiles x 8 col-pairs; each block owns 2 col tiles.
    const int lin    = blockIdx.y * 32 + blockIdx.x;   // 0..2047
    const int xcd    = lin & 7;
    const int within = lin >> 3;        // 0..255
    const int txp    = within & 7;      // col-pair inside region, 0..7
    const int ty     = within >> 3;     // row tile inside region, 0..31
    const int m0  = ((xcd >> 2) * 32 + ty) * 128;
    const int n0a = ((xcd & 3) * 16 + txp * 2) * 128;      // ct0
    const int n0b = n0a + 128;                              // ct1

    const int wr   = (wave >> 1) * 32;  // 4 row groups of 32
    const int wc   = (wave & 1) * 64;   // 2 col groups of 64

    // ---- hoisted epilogue constants: row side (shared) + BOTH col tiles ----
    float na[8]; int gr[8];
    #pragma unroll
    for (int mi = 0; mi < 2; ++mi)
        #pragma unroll
        for (int r = 0; r < 4; ++r) {
            int row = m0 + wr + mi*16 + quad*4 + r;
            na[mi*4 + r] = normN[row];
            gr[mi*4 + r] = node_batch[row];
        }
    const int rlo = node_batch[m0 + wr], rhi = node_batch[m0 + wr + 31];

    float nbA[4], nbB[4]; int glA[4], glB[4];
    #pragma unroll
    for (int ni = 0; ni < 4; ++ni) {
        int colA = n0a + wc + ni*16 + lc;
        int colB = n0b + wc + ni*16 + lc;
        nbA[ni] = normL[colA];  glA[ni] = label_batch[colA];
        nbB[ni] = normL[colB];  glB[ni] = label_batch[colB];
    }
    const int gloA = label_batch[n0a + wc], ghiA = label_batch[n0a + wc + 63];
    const int gloB = label_batch[n0b + wc], ghiB = label_batch[n0b + wc + 63];

    f32x4 acc[2][4];
    auto zero_acc = [&]() {
        #pragma unroll
        for (int i = 0; i < 2; ++i)
            #pragma unroll
            for (int j = 0; j < 4; ++j) {
                f32x4 z = {0.f, 0.f, 0.f, 0.f};
                acc[i][j] = z;
            }
    };
    zero_acc();

    // stage tiles for K-step kt of col-tile at n0t into LDS buffer `buf`;
    // phys chunk (row, cc) holds global chunk (row, cc^(row&7)); 4 glds/thread
    auto stage = [&](int buf, int n0t, int kt) {
        #pragma unroll
        for (int t = 0; t < 2; ++t) {
            int c = t * 512 + tid;              // chunk id, linear in tid
            int row = c >> 3, cc = c & 7;
            int scc = cc ^ (row & 7);
            const unsigned short* gp = A + (size_t)(m0 + row) * D + kt * 64 + scc * 8;
            __builtin_amdgcn_global_load_lds(
                (const __attribute__((address_space(1))) void*)gp,
                (__attribute__((address_space(3))) void*)(As[buf] + c * 8), 16, 0, 0);
        }
        #pragma unroll
        for (int t = 0; t < 2; ++t) {
            int c = t * 512 + tid;
            int row = c >> 3, cc = c & 7;
            int scc = cc ^ (row & 7);
            const unsigned short* gp = B + (size_t)(n0t + row) * D + kt * 64 + scc * 8;
            __builtin_amdgcn_global_load_lds(
                (const __attribute__((address_space(1))) void*)gp,
                (__attribute__((address_space(3))) void*)(Bs[buf] + c * 8), 16, 0, 0);
        }
    };

    // one K=64 tile of MFMAs from buffer pair (Asb, Bsb)
    auto compute = [&](const unsigned short* Asb, const unsigned short* Bsb) {
        #pragma unroll
        for (int kk = 0; kk < 2; ++kk) {        // two k=32 steps
            bf16x8 af[2], bfv[4];
            #pragma unroll
            for (int mi = 0; mi < 2; ++mi)
                af[mi] = *(const bf16x8*)(Asb + (wr + mi*16 + lc) * 64
                                             + ((kk*4 + quad) ^ (lc & 7)) * 8);
            #pragma unroll
            for (int ni = 0; ni < 4; ++ni)
                bfv[ni] = *(const bf16x8*)(Bsb + (wc + ni*16 + lc) * 64
                                              + ((kk*4 + quad) ^ (lc & 7)) * 8);
            __builtin_amdgcn_s_setprio(1);
            #pragma unroll
            for (int mi = 0; mi < 2; ++mi)
                #pragma unroll
                for (int ni = 0; ni < 4; ++ni)
                    acc[mi][ni] = __builtin_amdgcn_mfma_f32_16x16x32_bf16(
                        af[mi], bfv[ni], acc[mi][ni], 0, 0, 0);
            __builtin_amdgcn_s_setprio(0);
        }
    };

    const float FINF = __uint_as_float(INF_BITS);

    // full epilogue for the tile at n0t (uses acc, na/gr/rlo/rhi)
    auto do_epilogue = [&](int n0t, const float* nb, const int* gl,
                           int glo, int ghi) {
        // dot -> clamped squared distance (in place); sqrt deferred
        #pragma unroll
        for (int mi = 0; mi < 2; ++mi)
            #pragma unroll
            for (int ni = 0; ni < 4; ++ni)
                #pragma unroll
                for (int r = 0; r < 4; ++r)
                    acc[mi][ni][r] = fmaxf(
                        fmaf(-2.0f, acc[mi][ni][r], na[mi*4 + r] + nb[ni]), 0.0f);

        // per-row min over columns, grouped by label graph
        if (glo == ghi) {
            float rm[8];
            #pragma unroll
            for (int mi = 0; mi < 2; ++mi)
                #pragma unroll
                for (int r = 0; r < 4; ++r) {
                    float m = fminf(fmin3(acc[mi][0][r], acc[mi][1][r], acc[mi][2][r]),
                                    acc[mi][3][r]);
                    rm[mi*4 + r] = dpp_min16(m);
                }
            if (lc == 0) {
                #pragma unroll
                for (int mi = 0; mi < 2; ++mi)
                    #pragma unroll
                    for (int r = 0; r < 4; ++r) {
                        int row = m0 + wr + mi*16 + quad*4 + r;
                        atomicMin(&bufN[row * NG + glo], __float_as_uint(rm[mi*4 + r]));
                    }
            }
        } else {
            for (int g = glo; g <= ghi; ++g) {
                bool s0 = (gl[0] == g), s1 = (gl[1] == g),
                     s2 = (gl[2] == g), s3 = (gl[3] == g);
                float rm[8];
                #pragma unroll
                for (int mi = 0; mi < 2; ++mi)
                    #pragma unroll
                    for (int r = 0; r < 4; ++r) {
                        float v0 = s0 ? acc[mi][0][r] : FINF;
                        float v1 = s1 ? acc[mi][1][r] : FINF;
                        float v2 = s2 ? acc[mi][2][r] : FINF;
                        float v3 = s3 ? acc[mi][3][r] : FINF;
                        rm[mi*4 + r] = dpp_min16(fminf(fmin3(v0, v1, v2), v3));
                    }
                if (lc == 0) {
                    #pragma unroll
                    for (int mi = 0; mi < 2; ++mi)
                        #pragma unroll
                        for (int r = 0; r < 4; ++r) {
                            int row = m0 + wr + mi*16 + quad*4 + r;
                            atomicMin(&bufN[row * NG + g], __float_as_uint(rm[mi*4 + r]));
                        }
                }
            }
        }

        // per-col min over rows, grouped by node graph
        if (rlo == rhi) {
            float cm[4];
            #pragma unroll
            for (int ni = 0; ni < 4; ++ni) {
                float m = fminf(fmin3(fmin3(acc[0][ni][0], acc[0][ni][1], acc[0][ni][2]),
                                      fmin3(acc[0][ni][3], acc[1][ni][0], acc[1][ni][1]),
                                      acc[1][ni][2]),
                                acc[1][ni][3]);
                m = pl16_min(m);
                m = pl32_min(m);
                cm[ni] = m;
            }
            if (quad == 0) {
                #pragma unroll
                for (int ni = 0; ni < 4; ++ni) {
                    int col = n0t + wc + ni*16 + lc;
                    atomicMin(&bufL[rlo * EL + col], __float_as_uint(cm[ni]));
                }
            }
        } else {
            for (int g = rlo; g <= rhi; ++g) {
                float cm[4];
                #pragma unroll
                for (int ni = 0; ni < 4; ++ni) {
                    float s[8];
                    #pragma unroll
                    for (int mi = 0; mi < 2; ++mi)
                        #pragma unroll
                        for (int r = 0; r < 4; ++r)
                            s[mi*4 + r] = (gr[mi*4 + r] == g) ? acc[mi][ni][r] : FINF;
                    float m = fminf(fmin3(fmin3(s[0], s[1], s[2]),
                                          fmin3(s[3], s[4], s[5]), s[6]),
                                    s[7]);
                    m = pl16_min(m);
                    m = pl32_min(m);
                    cm[ni] = m;
                }
                if (quad == 0) {
                    #pragma unroll
                    for (int ni = 0; ni < 4; ++ni) {
                        int col = n0t + wc + ni*16 + lc;
                        atomicMin(&bufL[g * EL + col], __float_as_uint(cm[ni]));
                    }
                }
            }
        }
    };

    // ---- continuous pipeline over 2 col tiles x 4 K-steps ----
    stage(0, n0a, 0);
    stage(1, n0a, 1);
    VMCNT4();                     // ct0k0 landed (ct0k1 in flight)
    BARRIER();

    compute(As[0], Bs[0]);        // ct0 kt0
    BARRIER();                    // readers of buf0 done
    stage(0, n0a, 2);
    VMCNT4();                     // ct0k1 landed
    BARRIER();

    compute(As[1], Bs[1]);        // ct0 kt1
    BARRIER();                    // readers of buf1 done
    stage(1, n0a, 3);
    VMCNT4();                     // ct0k2 landed
    BARRIER();

    compute(As[0], Bs[0]);        // ct0 kt2
    BARRIER();                    // readers of buf0 done
    stage(0, n0b, 0);             // ct1 k0 into buf0 (pipeline stays hot)
    VMCNT4();                     // ct0k3 landed (ct1k0 in flight)
    BARRIER();

    compute(As[1], Bs[1]);        // ct0 kt3 -> acc complete for ct0
    BARRIER();                    // readers of buf1 done
    stage(1, n0b, 1);             // ct1 k1 into buf1
    VMCNT4();                     // ct1k0 landed (ct1k1 in flight)
    do_epilogue(n0a, nbA, glA, gloA, ghiA);   // overlaps ct1k1 flight
    zero_acc();
    BARRIER();                    // all waves: epilogue done, ct1k0 visible

    compute(As[0], Bs[0]);        // ct1 kt0
    BARRIER();
    stage(0, n0b, 2);
    VMCNT4();                     // ct1k1 (+ atomics) drained conservatively
    BARRIER();

    compute(As[1], Bs[1]);        // ct1 kt1
    BARRIER();
    stage(1, n0b, 3);
    VMCNT4();                     // ct1k2 landed
    BARRIER();

    compute(As[0], Bs[0]);        // ct1 kt2
    VMCNT0();                     // ct1k3 landed
    BARRIER();

    compute(As[1], Bs[1]);        // ct1 kt3

    do_epilogue(n0b, nbB, glB, gloB, ghiB);
}

// ---------------- kernel 3: segment means + combine ----------------
__device__ __forceinline__ int lbound(const int* __restrict__ a, int n, int v) {
    int lo = 0, hi = n;
    while (lo < hi) { int mid = (lo + hi) >> 1; if (a[mid] < v) lo = mid + 1; else hi = mid; }
    return lo;
}

// one block per node-graph gn; MUST be launched with 1024 threads
__global__ void finalize(const unsigned* __restrict__ bufN,
                         const unsigned* __restrict__ bufL,
                         const int* __restrict__ node_batch,
                         const int* __restrict__ label_batch,
                         float* __restrict__ out)
{
    __shared__ float sN[NG];   // sum over rows of -dist, per label graph
    __shared__ float sL[NG];   // sum over cols of -dist, per label graph
    int gn  = blockIdx.x;
    int tid = threadIdx.x;
    if (tid < NG) { sN[tid] = 0.0f; sL[tid] = 0.0f; }
    __syncthreads();

    int ns = lbound(node_batch, EN, gn);
    int ne = lbound(node_batch, EN, gn + 1);

    // part 1: bufN slice [ns:ne) x NG -> per-label sums (coalesced across t)
    {
        int t = tid & 63, strip = tid >> 6;          // 16 row strips
        float acc = 0.0f;
        for (int i = ns + strip; i < ne; i += 16) {
            unsigned b = bufN[i * NG + t];
            if (b != INF_BITS) acc -= sqrtf(__uint_as_float(b));
        }
        atomicAdd(&sN[t], acc);
    }

    // part 2: bufL row gn (8192 cols, coalesced), scatter by label graph
    for (int j = tid; j < EL; j += 1024) {
        unsigned b = bufL[gn * EL + j];
        if (b != INF_BITS) {
            int g = label_batch[j];
            atomicAdd(&sL[g], -sqrtf(__uint_as_float(b)));
        }
    }
    __syncthreads();

    if (tid < NG) {
        int t = tid;
        int cn = ne - ns;
        int ls = lbound(label_batch, EL, t);
        int le = lbound(label_batch, EL, t + 1);
        int cl = le - ls;
        float out_n = sN[t] / (float)(cn > 0 ? cn : 1);
        float out_l = sL[t] / (float)(cl > 0 ? cl : 1);
        out[gn * NG + t] = 0.5f * (out_n + out_l);
    }
}

extern "C" void kernel_launch(void* const* d_in, const int* in_sizes, int n_in,
                              void* d_out, int out_size, void* d_ws, size_t ws_size,
                              hipStream_t stream)
{
    const float* h          = (const float*)d_in[0];
    const int* node_edge    = (const int*)d_in[1];
    const int* node_batch   = (const int*)d_in[2];
    const int* label_edge   = (const int*)d_in[3];
    const int* label_batch  = (const int*)d_in[4];
    float* out = (float*)d_out;

    char* ws = (char*)d_ws;
    unsigned short* efn = (unsigned short*)ws; ws += (size_t)EN * D * 2;
    unsigned short* efl = (unsigned short*)ws; ws += (size_t)EL * D * 2;
    float* normN = (float*)ws;                 ws += (size_t)EN * 4;
    float* normL = (float*)ws;                 ws += (size_t)EL * 4;
    unsigned* bufN = (unsigned*)ws;            ws += (size_t)EN * NG * 4;
    unsigned* bufL = (unsigned*)ws;            ws += (size_t)NG * EL * 4;

    // bufN,bufL contiguous: 1024 init blocks + 2048 + 2048 edge blocks
    prep<<<5120, 256, 0, stream>>>(h, node_edge, label_edge,
                                   efn, normN, efl, normL, bufN);
    dist_min<<<dim3(32, 64), 512, 0, stream>>>(
        efn, efl, normN, normL, node_batch, label_batch, bufN, bufL);
    finalize<<<NG, 1024, 0, stream>>>(bufN, bufL, node_batch, label_batch, out);
}